// Round 8
// baseline (342.006 us; speedup 1.0000x reference)
//
#include <hip/hip_runtime.h>
#include <hip/hip_bf16.h>
#include <math.h>

// Problem constants (from reference)
#define N_NODES_C 100000
#define E_ORIG    400000
#define E_TOT     500000   // + self loops
#define N_GRAPHS_C 2000
#define KDIM      256      // HEADS*HID = OUT

typedef __attribute__((ext_vector_type(8))) short short8v;  // 8 bf16 = 4 VGPR
typedef __attribute__((ext_vector_type(4))) float f32x4;

__device__ __forceinline__ void gload_lds16(const void* g, void* l) {
    __builtin_amdgcn_global_load_lds(
        (const __attribute__((address_space(1))) unsigned int*)g,
        (__attribute__((address_space(3))) unsigned int*)l, 16, 0, 0);
}

__device__ __forceinline__ float bflo(unsigned u) { return __uint_as_float(u << 16); }
__device__ __forceinline__ float bfhi(unsigned u) { return __uint_as_float(u & 0xffff0000u); }

// ---------------------------------------------------------------------------
// CSR construction (by destination). Graph is identical for all 3 layers.
// ---------------------------------------------------------------------------
__global__ void count_deg_k(const int* __restrict__ ei, int* __restrict__ deg) {
    int e = blockIdx.x * 256 + threadIdx.x;
    if (e >= E_TOT) return;
    int d = (e < E_ORIG) ? ei[E_ORIG + e] : (e - E_ORIG);
    atomicAdd(&deg[d], 1);
}

__global__ void scan_chunk(const int* __restrict__ in, int* __restrict__ out,
                           int* __restrict__ partials, int n) {
    __shared__ int s[256];
    int tid = threadIdx.x;
    int i = blockIdx.x * 256 + tid;
    int v = (i < n) ? in[i] : 0;
    s[tid] = v;
    __syncthreads();
    for (int off = 1; off < 256; off <<= 1) {
        int t = (tid >= off) ? s[tid - off] : 0;
        __syncthreads();
        s[tid] += t;
        __syncthreads();
    }
    if (i < n) out[i] = s[tid] - v;            // exclusive
    if (tid == 255) partials[blockIdx.x] = s[255];
}

__global__ void scan_partials(int* p, int nb) {
    __shared__ int s[512];
    int tid = threadIdx.x;
    int v = (tid < nb) ? p[tid] : 0;
    s[tid] = v;
    __syncthreads();
    for (int off = 1; off < 512; off <<= 1) {
        int t = (tid >= off) ? s[tid - off] : 0;
        __syncthreads();
        s[tid] += t;
        __syncthreads();
    }
    if (tid < nb) p[tid] = s[tid] - v;         // exclusive
}

__global__ void add_partials(int* out, const int* __restrict__ p, int n) {
    int i = blockIdx.x * 256 + threadIdx.x;
    if (i < n) out[i] += p[blockIdx.x];
}

__global__ void scatter_k(const int* __restrict__ ei, const int* __restrict__ rowoff,
                          int* cursor, int* __restrict__ csr_src,
                          int* __restrict__ csr_dst) {
    int e = blockIdx.x * 256 + threadIdx.x;
    if (e >= E_TOT) return;
    int s, d;
    if (e < E_ORIG) { s = ei[e]; d = ei[E_ORIG + e]; }
    else            { s = e - E_ORIG; d = s; }
    int pos = rowoff[d] + atomicAdd(&cursor[d], 1);
    csr_src[pos] = s;
    csr_dst[pos] = d;
}

// ---------------------------------------------------------------------------
// All input conversions to bf16 in ONE kernel (4 regions by flat index).
// ---------------------------------------------------------------------------
#define XE  (N_NODES_C * 64)
#define W1E (256 * 64)
#define WBE (256 * 256)
__global__ __launch_bounds__(256) void conv_all_k(
        const float* __restrict__ x, const float* __restrict__ W1,
        const float* __restrict__ W2, const float* __restrict__ W3,
        __hip_bfloat16* __restrict__ Xb, __hip_bfloat16* __restrict__ Wt1,
        __hip_bfloat16* __restrict__ Wt2, __hip_bfloat16* __restrict__ Wt3) {
    int idx = blockIdx.x * 256 + threadIdx.x;
    if (idx < XE) {
        int row = idx >> 6, c = idx & 63;
        float v = (c < 58) ? x[row * 58 + c] : 0.f;
        Xb[idx] = __float2bfloat16(v);
    } else if (idx < XE + W1E) {
        int i = idx - XE;
        int c = i >> 6, k = i & 63;               // KPAD=64, K=58
        float v = (k < 58) ? W1[k * 256 + c] : 0.f;
        Wt1[i] = __float2bfloat16(v);
    } else if (idx < XE + W1E + WBE) {
        int i = idx - XE - W1E;
        int c = i >> 8, k = i & 255;
        Wt2[i] = __float2bfloat16(W2[k * 256 + c]);
    } else if (idx < XE + W1E + 2 * WBE) {
        int i = idx - XE - W1E - WBE;
        int c = i >> 8, k = i & 255;
        Wt3[i] = __float2bfloat16(W3[k * 256 + c]);
    }
}

// ---------------------------------------------------------------------------
// MFMA bf16 GEMM: H = X @ W  (X:[N][KPAD] bf16, Wt:[256 cols][KPAD] bf16)
// + fused attention dots ES/ED. (unchanged from r7 — verified)
// Block: 128 rows x 256 cols, 4 waves, wave tile 64x128, BK=64, chunk-XOR
// swizzled LDS staged via global_load_lds.
// ---------------------------------------------------------------------------
template <int KPAD, int NH>
__global__ __launch_bounds__(256, 2) void gemm_mfma(
        const __hip_bfloat16* __restrict__ Xb, const __hip_bfloat16* __restrict__ Wt,
        const float* __restrict__ ASRC, const float* __restrict__ ADST,
        __hip_bfloat16* __restrict__ H, float* __restrict__ ES, float* __restrict__ ED) {
    __shared__ char As[128 * 128];                   // [128 rows][64 k] bf16
    __shared__ char Bs[256 * 128];                   // [256 cols][64 k] bf16
    __shared__ float red[2][128][2];                 // NH==1 cross-wave ES/ED

    const int t = threadIdx.x;
    const int wv = t >> 6, lane = t & 63;
    const int wr = wv >> 1, wc = wv & 1;
    const int r15 = lane & 15, hi = lane >> 4;
    const int n0 = blockIdx.x * 128;
    const int srow = lane >> 3;                      // staging: row-within-8
    const int sx = ((lane & 7) ^ srow) * 16;         // pre-swizzled source chunk
    constexpr int KB = KPAD * 2;                     // row bytes

    f32x4 acc[4][8];
#pragma unroll
    for (int m = 0; m < 4; m++)
#pragma unroll
        for (int n = 0; n < 8; n++) acc[m][n] = (f32x4){0.f, 0.f, 0.f, 0.f};

    for (int kt = 0; kt < KPAD / 64; kt++) {
        if (kt) __syncthreads();
        const int k0b = kt * 128;
#pragma unroll
        for (int p = 0; p < 4; p++) {
            int i = wv * 4 + p;
            int gr = n0 + i * 8 + srow;
            if (gr > N_NODES_C - 1) gr = N_NODES_C - 1;
            gload_lds16((const char*)Xb + (size_t)gr * KB + k0b + sx, As + i * 1024);
        }
#pragma unroll
        for (int p = 0; p < 8; p++) {
            int i = wv * 8 + p;
            int col = i * 8 + srow;
            gload_lds16((const char*)Wt + (size_t)col * KB + k0b + sx, Bs + i * 1024);
        }
        asm volatile("s_waitcnt vmcnt(0)" ::: "memory");
        __syncthreads();

#pragma unroll
        for (int ks = 0; ks < 2; ks++) {
            const int cx = ((ks * 4 + hi) ^ (r15 & 7)) * 16;  // swizzled chunk byte
            short8v a[4];
#pragma unroll
            for (int m = 0; m < 4; m++)
                a[m] = *(const short8v*)(As + (wr * 64 + m * 16 + r15) * 128 + cx);
#pragma unroll
            for (int n = 0; n < 8; n++) {
                short8v b = *(const short8v*)(Bs + (wc * 128 + n * 16 + r15) * 128 + cx);
#pragma unroll
                for (int m = 0; m < 4; m++)
                    acc[m][n] = __builtin_amdgcn_mfma_f32_16x16x32_bf16(a[m], b, acc[m][n], 0, 0, 0);
            }
        }
    }

    // ---- epilogue: H (bf16) + attention dots ----
    float asv[8], adv[8];
#pragma unroll
    for (int n = 0; n < 8; n++) {
        int col = wc * 128 + n * 16 + r15;
        asv[n] = ASRC[col];
        adv[n] = ADST[col];
    }

#pragma unroll
    for (int m = 0; m < 4; m++) {
#pragma unroll
        for (int j = 0; j < 4; j++) {
            int lrow = wr * 64 + m * 16 + hi * 4 + j;
            int row = n0 + lrow;
            bool ok = row < N_NODES_C;
            if (ok) {
#pragma unroll
                for (int n = 0; n < 8; n++)
                    H[(size_t)row * KDIM + wc * 128 + n * 16 + r15] =
                        __float2bfloat16(acc[m][n][j]);
            }
            if (NH == 4) {
                float p0s = 0.f, p1s = 0.f, p0d = 0.f, p1d = 0.f;
#pragma unroll
                for (int n = 0; n < 4; n++) {
                    p0s = fmaf(acc[m][n][j], asv[n], p0s);
                    p0d = fmaf(acc[m][n][j], adv[n], p0d);
                    p1s = fmaf(acc[m][n + 4][j], asv[n + 4], p1s);
                    p1d = fmaf(acc[m][n + 4][j], adv[n + 4], p1d);
                }
#pragma unroll
                for (int s = 8; s; s >>= 1) {
                    p0s += __shfl_xor(p0s, s, 16);
                    p0d += __shfl_xor(p0d, s, 16);
                    p1s += __shfl_xor(p1s, s, 16);
                    p1d += __shfl_xor(p1d, s, 16);
                }
                if (r15 == 0 && ok) {
                    ES[row * 4 + wc * 2 + 0] = p0s;
                    ES[row * 4 + wc * 2 + 1] = p1s;
                    ED[row * 4 + wc * 2 + 0] = p0d;
                    ED[row * 4 + wc * 2 + 1] = p1d;
                }
            } else {
                float ps = 0.f, pd = 0.f;
#pragma unroll
                for (int n = 0; n < 8; n++) {
                    ps = fmaf(acc[m][n][j], asv[n], ps);
                    pd = fmaf(acc[m][n][j], adv[n], pd);
                }
#pragma unroll
                for (int s = 8; s; s >>= 1) {
                    ps += __shfl_xor(ps, s, 16);
                    pd += __shfl_xor(pd, s, 16);
                }
                if (r15 == 0) { red[0][lrow][wc] = ps; red[1][lrow][wc] = pd; }
            }
        }
    }
    if (NH == 1) {
        __syncthreads();
        if (t < 128) {
            int row = n0 + t;
            if (row < N_NODES_C) {
                ES[row] = red[0][t][0] + red[0][t][1];
                ED[row] = red[1][t][0] + red[1][t][1];
            }
        }
    }
}

// ---------------------------------------------------------------------------
// Edge-parallel logit precompute: E[slot][h] = leaky_relu(ES[src,h]+ED[dst,h])
// ---------------------------------------------------------------------------
template <int NH>
__global__ __launch_bounds__(256) void edge_e_k(
        const int* __restrict__ csr_src, const int* __restrict__ csr_dst,
        const float* __restrict__ ES, const float* __restrict__ ED,
        float* __restrict__ E) {
    int j = blockIdx.x * 256 + threadIdx.x;
    if (j >= E_TOT) return;
    int s = csr_src[j], d = csr_dst[j];
    if (NH == 4) {
        float4 es = *(const float4*)&ES[s * 4];
        float4 ed = *(const float4*)&ED[d * 4];
        float4 e;
        e.x = es.x + ed.x; e.x = (e.x > 0.f) ? e.x : 0.2f * e.x;
        e.y = es.y + ed.y; e.y = (e.y > 0.f) ? e.y : 0.2f * e.y;
        e.z = es.z + ed.z; e.z = (e.z > 0.f) ? e.z : 0.2f * e.z;
        e.w = es.w + ed.w; e.w = (e.w > 0.f) ? e.w : 0.2f * e.w;
        *(float4*)&E[j * 4] = e;
    } else {
        float e = ES[s] + ED[d];
        E[j] = (e > 0.f) ? e : 0.2f * e;
    }
}

// ---------------------------------------------------------------------------
// Per-dst softmax aggregation: 16 lanes per node (16 nodes/block), lane owns
// 16 channels -> TWO independent uint4 gathers per edge; 4-wide unroll keeps
// 8 H-gathers in flight per lane group. Logits precomputed & contiguous in E.
// ---------------------------------------------------------------------------
template <int NH, bool RELU>
__global__ __launch_bounds__(256) void agg_kernel(
        const __hip_bfloat16* __restrict__ H, const int* __restrict__ rowoff,
        const int* __restrict__ csr_src, const float* __restrict__ E,
        const float* __restrict__ bias, __hip_bfloat16* __restrict__ Out) {
    int node = blockIdx.x * 16 + (threadIdx.x >> 4);  // grid*16 == N exactly
    int l = threadIdx.x & 15;
    int c0 = l * 16;                                  // 16 channels: c0..c0+15
    int head = (NH == 4) ? (l >> 2) : 0;
    int beg = rowoff[node], end = rowoff[node + 1];

    float m = -1e30f;
    for (int j = beg; j < end; j++) m = fmaxf(m, E[j * NH + head]);

    float s = 0.f;
    float a[16];
#pragma unroll
    for (int i = 0; i < 16; i++) a[i] = 0.f;
    const unsigned short* Hu = (const unsigned short*)H;

#define ACCV(va, vb, p) \
    a[0]  = fmaf(p, bflo(va.x), a[0]);  a[1]  = fmaf(p, bfhi(va.x), a[1]); \
    a[2]  = fmaf(p, bflo(va.y), a[2]);  a[3]  = fmaf(p, bfhi(va.y), a[3]); \
    a[4]  = fmaf(p, bflo(va.z), a[4]);  a[5]  = fmaf(p, bfhi(va.z), a[5]); \
    a[6]  = fmaf(p, bflo(va.w), a[6]);  a[7]  = fmaf(p, bfhi(va.w), a[7]); \
    a[8]  = fmaf(p, bflo(vb.x), a[8]);  a[9]  = fmaf(p, bfhi(vb.x), a[9]); \
    a[10] = fmaf(p, bflo(vb.y), a[10]); a[11] = fmaf(p, bfhi(vb.y), a[11]); \
    a[12] = fmaf(p, bflo(vb.z), a[12]); a[13] = fmaf(p, bfhi(vb.z), a[13]); \
    a[14] = fmaf(p, bflo(vb.w), a[14]); a[15] = fmaf(p, bfhi(vb.w), a[15]);

    int j = beg;
    for (; j + 4 <= end; j += 4) {
        int s0 = csr_src[j], s1 = csr_src[j + 1], s2 = csr_src[j + 2], s3 = csr_src[j + 3];
        float e0 = E[(j + 0) * NH + head], e1 = E[(j + 1) * NH + head];
        float e2 = E[(j + 2) * NH + head], e3 = E[(j + 3) * NH + head];
        uint4 v0a = *(const uint4*)(Hu + (size_t)s0 * KDIM + c0);
        uint4 v0b = *(const uint4*)(Hu + (size_t)s0 * KDIM + c0 + 8);
        uint4 v1a = *(const uint4*)(Hu + (size_t)s1 * KDIM + c0);
        uint4 v1b = *(const uint4*)(Hu + (size_t)s1 * KDIM + c0 + 8);
        uint4 v2a = *(const uint4*)(Hu + (size_t)s2 * KDIM + c0);
        uint4 v2b = *(const uint4*)(Hu + (size_t)s2 * KDIM + c0 + 8);
        uint4 v3a = *(const uint4*)(Hu + (size_t)s3 * KDIM + c0);
        uint4 v3b = *(const uint4*)(Hu + (size_t)s3 * KDIM + c0 + 8);
        float p0 = __expf(e0 - m), p1 = __expf(e1 - m);
        float p2 = __expf(e2 - m), p3 = __expf(e3 - m);
        s += p0 + p1 + p2 + p3;
        ACCV(v0a, v0b, p0)
        ACCV(v1a, v1b, p1)
        ACCV(v2a, v2b, p2)
        ACCV(v3a, v3b, p3)
    }
    for (; j < end; j++) {
        int s0 = csr_src[j];
        float e0 = E[j * NH + head];
        uint4 va = *(const uint4*)(Hu + (size_t)s0 * KDIM + c0);
        uint4 vb = *(const uint4*)(Hu + (size_t)s0 * KDIM + c0 + 8);
        float p0 = __expf(e0 - m);
        s += p0;
        ACCV(va, vb, p0)
    }
#undef ACCV

    float inv = 1.f / s;
    __hip_bfloat16 rb[16];
#pragma unroll
    for (int q = 0; q < 4; q++) {
        float4 b4 = *(const float4*)&bias[c0 + q * 4];
        float o0 = fmaf(a[q * 4 + 0], inv, b4.x);
        float o1 = fmaf(a[q * 4 + 1], inv, b4.y);
        float o2 = fmaf(a[q * 4 + 2], inv, b4.z);
        float o3 = fmaf(a[q * 4 + 3], inv, b4.w);
        if (RELU) {
            o0 = fmaxf(o0, 0.f); o1 = fmaxf(o1, 0.f);
            o2 = fmaxf(o2, 0.f); o3 = fmaxf(o3, 0.f);
        }
        rb[q * 4 + 0] = __float2bfloat16(o0);
        rb[q * 4 + 1] = __float2bfloat16(o1);
        rb[q * 4 + 2] = __float2bfloat16(o2);
        rb[q * 4 + 3] = __float2bfloat16(o3);
    }
    *(uint4*)&Out[(size_t)node * KDIM + c0] = *(uint4*)&rb[0];
    *(uint4*)&Out[(size_t)node * KDIM + c0 + 8] = *(uint4*)&rb[8];
}

// ---------------------------------------------------------------------------
// Global max pool over graphs. 4 rows in flight (wave = row offset), uint2
// loads (4 bf16 channels/thread), LDS cross-wave combine.
// ---------------------------------------------------------------------------
__global__ __launch_bounds__(256) void pool_k(
        const __hip_bfloat16* __restrict__ O, const int* __restrict__ batch,
        float* __restrict__ out) {
    __shared__ int range[2];
    __shared__ float red[3][256];
    int g = blockIdx.x, k = threadIdx.x;
    if (k < 2) {
        int v = g + k;
        int lo = 0, hi = N_NODES_C;
        while (lo < hi) { int mid = (lo + hi) >> 1; if (batch[mid] < v) lo = mid + 1; else hi = mid; }
        range[k] = lo;
    }
    __syncthreads();
    int cg = k & 63;                 // channels cg*4 .. cg*4+3
    int ro = k >> 6;                 // wave = row offset
    float m0 = -INFINITY, m1 = -INFINITY, m2 = -INFINITY, m3 = -INFINITY;
    const unsigned short* Ou = (const unsigned short*)O;
    for (int i = range[0] + ro; i < range[1]; i += 4) {
        uint2 v = *(const uint2*)(Ou + (size_t)i * KDIM + cg * 4);
        m0 = fmaxf(m0, bflo(v.x)); m1 = fmaxf(m1, bfhi(v.x));
        m2 = fmaxf(m2, bflo(v.y)); m3 = fmaxf(m3, bfhi(v.y));
    }
    if (ro) {
        red[ro - 1][cg * 4 + 0] = m0; red[ro - 1][cg * 4 + 1] = m1;
        red[ro - 1][cg * 4 + 2] = m2; red[ro - 1][cg * 4 + 3] = m3;
    }
    __syncthreads();
    if (ro == 0) {
        m0 = fmaxf(fmaxf(m0, red[0][cg * 4 + 0]), fmaxf(red[1][cg * 4 + 0], red[2][cg * 4 + 0]));
        m1 = fmaxf(fmaxf(m1, red[0][cg * 4 + 1]), fmaxf(red[1][cg * 4 + 1], red[2][cg * 4 + 1]));
        m2 = fmaxf(fmaxf(m2, red[0][cg * 4 + 2]), fmaxf(red[1][cg * 4 + 2], red[2][cg * 4 + 2]));
        m3 = fmaxf(fmaxf(m3, red[0][cg * 4 + 3]), fmaxf(red[1][cg * 4 + 3], red[2][cg * 4 + 3]));
        float4 o = make_float4(m0, m1, m2, m3);
        *(float4*)&out[(size_t)g * KDIM + cg * 4] = o;
    }
}

// ---------------------------------------------------------------------------
extern "C" void kernel_launch(void* const* d_in, const int* in_sizes, int n_in,
                              void* d_out, int out_size, void* d_ws, size_t ws_size,
                              hipStream_t stream) {
    const float* x     = (const float*)d_in[0];
    const int*   ei    = (const int*)d_in[1];
    const int*   batch = (const int*)d_in[2];
    const float* W1  = (const float*)d_in[3];
    const float* as1 = (const float*)d_in[4];
    const float* ad1 = (const float*)d_in[5];
    const float* b1  = (const float*)d_in[6];
    const float* W2  = (const float*)d_in[7];
    const float* as2 = (const float*)d_in[8];
    const float* ad2 = (const float*)d_in[9];
    const float* b2  = (const float*)d_in[10];
    const float* W3  = (const float*)d_in[11];
    const float* as3 = (const float*)d_in[12];
    const float* ad3 = (const float*)d_in[13];
    const float* b3  = (const float*)d_in[14];
    float* out = (float*)d_out;

    // Workspace layout (~135 MB)
    char* p = (char*)d_ws;
    auto alloc = [&](size_t bytes) { char* r = p; p += (bytes + 255) & ~(size_t)255; return r; };
    __hip_bfloat16* Xb  = (__hip_bfloat16*)alloc((size_t)N_NODES_C * 64 * 2);
    __hip_bfloat16* Hb  = (__hip_bfloat16*)alloc((size_t)N_NODES_C * KDIM * 2);
    __hip_bfloat16* Nb  = (__hip_bfloat16*)alloc((size_t)N_NODES_C * KDIM * 2);
    __hip_bfloat16* Wt1 = (__hip_bfloat16*)alloc(256 * 64 * 2);
    __hip_bfloat16* Wt2 = (__hip_bfloat16*)alloc(256 * 256 * 2);
    __hip_bfloat16* Wt3 = (__hip_bfloat16*)alloc(256 * 256 * 2);
    float* ES     = (float*)alloc((size_t)N_NODES_C * 4 * 4);
    float* ED     = (float*)alloc((size_t)N_NODES_C * 4 * 4);
    float* Ecoef  = (float*)alloc((size_t)E_TOT * 4 * 4);
    int* degcur   = (int*)alloc((size_t)(2 * N_NODES_C + 1) * 4);   // deg + cursor, one memset
    int* deg      = degcur;
    int* cursor   = degcur + (N_NODES_C + 1);
    int* rowoff   = (int*)alloc((N_NODES_C + 1) * 4);
    int* csr      = (int*)alloc((size_t)E_TOT * 4 + 256);   // +pad
    int* csrd     = (int*)alloc((size_t)E_TOT * 4);
    int* partials = (int*)alloc(512 * 4);

    // --- input conversions (one kernel) ---
    int ctot = XE + W1E + 2 * WBE;
    conv_all_k<<<(ctot + 255) / 256, 256, 0, stream>>>(x, W1, W2, W3, Xb, Wt1, Wt2, Wt3);

    // --- build CSR ---
    hipMemsetAsync(degcur, 0, (size_t)(2 * N_NODES_C + 1) * 4, stream);
    int egrid = (E_TOT + 255) / 256;
    count_deg_k<<<egrid, 256, 0, stream>>>(ei, deg);
    int nb = (N_NODES_C + 1 + 255) / 256;           // 391
    scan_chunk<<<nb, 256, 0, stream>>>(deg, rowoff, partials, N_NODES_C + 1);
    scan_partials<<<1, 512, 0, stream>>>(partials, nb);
    add_partials<<<nb, 256, 0, stream>>>(rowoff, partials, N_NODES_C + 1);
    scatter_k<<<egrid, 256, 0, stream>>>(ei, rowoff, cursor, csr, csrd);

    int ggrid = (N_NODES_C + 127) / 128;             // 782
    int agrid = N_NODES_C / 16;                      // 6250 (exact)
    // --- layer 1: 58(->64) -> 4x64, relu ---
    gemm_mfma<64, 4><<<ggrid, 256, 0, stream>>>(Xb, Wt1, as1, ad1, Hb, ES, ED);
    edge_e_k<4><<<egrid, 256, 0, stream>>>(csr, csrd, ES, ED, Ecoef);
    agg_kernel<4, true><<<agrid, 256, 0, stream>>>(Hb, rowoff, csr, Ecoef, b1, Nb);
    // --- layer 2: 256 -> 4x64, relu ---
    gemm_mfma<256, 4><<<ggrid, 256, 0, stream>>>(Nb, Wt2, as2, ad2, Hb, ES, ED);
    edge_e_k<4><<<egrid, 256, 0, stream>>>(csr, csrd, ES, ED, Ecoef);
    agg_kernel<4, true><<<agrid, 256, 0, stream>>>(Hb, rowoff, csr, Ecoef, b2, Nb);
    // --- layer 3: 256 -> 1x256, no relu ---
    gemm_mfma<256, 1><<<ggrid, 256, 0, stream>>>(Nb, Wt3, as3, ad3, Hb, ES, ED);
    edge_e_k<1><<<egrid, 256, 0, stream>>>(csr, csrd, ES, ED, Ecoef);
    agg_kernel<1, false><<<agrid, 256, 0, stream>>>(Hb, rowoff, csr, Ecoef, b3, Nb);
    // --- global max pool ---
    pool_k<<<N_GRAPHS_C, 256, 0, stream>>>(Nb, batch, out);
}

// Round 9
// 318.133 us; speedup vs baseline: 1.0750x; 1.0750x over previous
//
#include <hip/hip_runtime.h>
#include <hip/hip_bf16.h>
#include <math.h>

// Problem constants (from reference)
#define N_NODES_C 100000
#define E_ORIG    400000
#define E_TOT     500000   // + self loops
#define N_GRAPHS_C 2000
#define KDIM      256      // HEADS*HID = OUT

typedef __attribute__((ext_vector_type(8))) short short8v;  // 8 bf16 = 4 VGPR
typedef __attribute__((ext_vector_type(4))) float f32x4;

__device__ __forceinline__ void gload_lds16(const void* g, void* l) {
    __builtin_amdgcn_global_load_lds(
        (const __attribute__((address_space(1))) unsigned int*)g,
        (__attribute__((address_space(3))) unsigned int*)l, 16, 0, 0);
}

__device__ __forceinline__ float bflo(unsigned u) { return __uint_as_float(u << 16); }
__device__ __forceinline__ float bfhi(unsigned u) { return __uint_as_float(u & 0xffff0000u); }

// ---------------------------------------------------------------------------
// Conversions to bf16 + degree count, ONE kernel (regions by flat index).
// deg must be zeroed by the preceding memset.
// ---------------------------------------------------------------------------
#define XE  (N_NODES_C * 64)
#define W1E (256 * 64)
#define WBE (256 * 256)
__global__ __launch_bounds__(256) void conv_all_count(
        const float* __restrict__ x, const float* __restrict__ W1,
        const float* __restrict__ W2, const float* __restrict__ W3,
        const int* __restrict__ ei,
        __hip_bfloat16* __restrict__ Xb, __hip_bfloat16* __restrict__ Wt1,
        __hip_bfloat16* __restrict__ Wt2, __hip_bfloat16* __restrict__ Wt3,
        int* __restrict__ deg) {
    int idx = blockIdx.x * 256 + threadIdx.x;
    if (idx < E_TOT) {
        int d = (idx < E_ORIG) ? ei[E_ORIG + idx] : (idx - E_ORIG);
        atomicAdd(&deg[d], 1);
    }
    if (idx < XE) {
        int row = idx >> 6, c = idx & 63;
        float v = (c < 58) ? x[row * 58 + c] : 0.f;
        Xb[idx] = __float2bfloat16(v);
    } else if (idx < XE + W1E) {
        int i = idx - XE;
        int c = i >> 6, k = i & 63;               // KPAD=64, K=58
        float v = (k < 58) ? W1[k * 256 + c] : 0.f;
        Wt1[i] = __float2bfloat16(v);
    } else if (idx < XE + W1E + WBE) {
        int i = idx - XE - W1E;
        int c = i >> 8, k = i & 255;
        Wt2[i] = __float2bfloat16(W2[k * 256 + c]);
    } else if (idx < XE + W1E + 2 * WBE) {
        int i = idx - XE - W1E - WBE;
        int c = i >> 8, k = i & 255;
        Wt3[i] = __float2bfloat16(W3[k * 256 + c]);
    }
}

// ---------------------------------------------------------------------------
// CSR scan: per-chunk exclusive scan + raw chunk sums, then fix-up kernel
// where each block sums the preceding partials itself (no 3rd pass).
// ---------------------------------------------------------------------------
__global__ void scan_chunk(const int* __restrict__ in, int* __restrict__ out,
                           int* __restrict__ partials, int n) {
    __shared__ int s[256];
    int tid = threadIdx.x;
    int i = blockIdx.x * 256 + tid;
    int v = (i < n) ? in[i] : 0;
    s[tid] = v;
    __syncthreads();
    for (int off = 1; off < 256; off <<= 1) {
        int t = (tid >= off) ? s[tid - off] : 0;
        __syncthreads();
        s[tid] += t;
        __syncthreads();
    }
    if (i < n) out[i] = s[tid] - v;            // exclusive within chunk
    if (tid == 255) partials[blockIdx.x] = s[255];
}

__global__ void scan_fix(int* __restrict__ rowoff, const int* __restrict__ partials, int n) {
    __shared__ int sred[256];
    int t = threadIdx.x;
    int acc = 0;
    for (int i = t; i < blockIdx.x; i += 256) acc += partials[i];
    sred[t] = acc;
    __syncthreads();
    for (int off = 128; off; off >>= 1) {
        if (t < off) sred[t] += sred[t + off];
        __syncthreads();
    }
    int base = sred[0];
    int i = blockIdx.x * 256 + t;
    if (i < n) rowoff[i] += base;
}

__global__ void scatter_k(const int* __restrict__ ei, const int* __restrict__ rowoff,
                          int* cursor, int* __restrict__ csr_src,
                          int* __restrict__ csr_dst) {
    int e = blockIdx.x * 256 + threadIdx.x;
    if (e >= E_TOT) return;
    int s, d;
    if (e < E_ORIG) { s = ei[e]; d = ei[E_ORIG + e]; }
    else            { s = e - E_ORIG; d = s; }
    int pos = rowoff[d] + atomicAdd(&cursor[d], 1);
    csr_src[pos] = s;
    csr_dst[pos] = d;
}

// ---------------------------------------------------------------------------
// MFMA bf16 GEMM: H = X @ W  (X:[N][KPAD] bf16, Wt:[256 cols][KPAD] bf16)
// + fused attention dots ES/ED. (unchanged — verified r7/r8)
// ---------------------------------------------------------------------------
template <int KPAD, int NH>
__global__ __launch_bounds__(256, 2) void gemm_mfma(
        const __hip_bfloat16* __restrict__ Xb, const __hip_bfloat16* __restrict__ Wt,
        const float* __restrict__ ASRC, const float* __restrict__ ADST,
        __hip_bfloat16* __restrict__ H, float* __restrict__ ES, float* __restrict__ ED) {
    __shared__ char As[128 * 128];                   // [128 rows][64 k] bf16
    __shared__ char Bs[256 * 128];                   // [256 cols][64 k] bf16
    __shared__ float red[2][128][2];                 // NH==1 cross-wave ES/ED

    const int t = threadIdx.x;
    const int wv = t >> 6, lane = t & 63;
    const int wr = wv >> 1, wc = wv & 1;
    const int r15 = lane & 15, hi = lane >> 4;
    const int n0 = blockIdx.x * 128;
    const int srow = lane >> 3;                      // staging: row-within-8
    const int sx = ((lane & 7) ^ srow) * 16;         // pre-swizzled source chunk
    constexpr int KB = KPAD * 2;                     // row bytes

    f32x4 acc[4][8];
#pragma unroll
    for (int m = 0; m < 4; m++)
#pragma unroll
        for (int n = 0; n < 8; n++) acc[m][n] = (f32x4){0.f, 0.f, 0.f, 0.f};

    for (int kt = 0; kt < KPAD / 64; kt++) {
        if (kt) __syncthreads();
        const int k0b = kt * 128;
#pragma unroll
        for (int p = 0; p < 4; p++) {
            int i = wv * 4 + p;
            int gr = n0 + i * 8 + srow;
            if (gr > N_NODES_C - 1) gr = N_NODES_C - 1;
            gload_lds16((const char*)Xb + (size_t)gr * KB + k0b + sx, As + i * 1024);
        }
#pragma unroll
        for (int p = 0; p < 8; p++) {
            int i = wv * 8 + p;
            int col = i * 8 + srow;
            gload_lds16((const char*)Wt + (size_t)col * KB + k0b + sx, Bs + i * 1024);
        }
        asm volatile("s_waitcnt vmcnt(0)" ::: "memory");
        __syncthreads();

#pragma unroll
        for (int ks = 0; ks < 2; ks++) {
            const int cx = ((ks * 4 + hi) ^ (r15 & 7)) * 16;  // swizzled chunk byte
            short8v a[4];
#pragma unroll
            for (int m = 0; m < 4; m++)
                a[m] = *(const short8v*)(As + (wr * 64 + m * 16 + r15) * 128 + cx);
#pragma unroll
            for (int n = 0; n < 8; n++) {
                short8v b = *(const short8v*)(Bs + (wc * 128 + n * 16 + r15) * 128 + cx);
#pragma unroll
                for (int m = 0; m < 4; m++)
                    acc[m][n] = __builtin_amdgcn_mfma_f32_16x16x32_bf16(a[m], b, acc[m][n], 0, 0, 0);
            }
        }
    }

    // ---- epilogue: H (bf16) + attention dots ----
    float asv[8], adv[8];
#pragma unroll
    for (int n = 0; n < 8; n++) {
        int col = wc * 128 + n * 16 + r15;
        asv[n] = ASRC[col];
        adv[n] = ADST[col];
    }

#pragma unroll
    for (int m = 0; m < 4; m++) {
#pragma unroll
        for (int j = 0; j < 4; j++) {
            int lrow = wr * 64 + m * 16 + hi * 4 + j;
            int row = n0 + lrow;
            bool ok = row < N_NODES_C;
            if (ok) {
#pragma unroll
                for (int n = 0; n < 8; n++)
                    H[(size_t)row * KDIM + wc * 128 + n * 16 + r15] =
                        __float2bfloat16(acc[m][n][j]);
            }
            if (NH == 4) {
                float p0s = 0.f, p1s = 0.f, p0d = 0.f, p1d = 0.f;
#pragma unroll
                for (int n = 0; n < 4; n++) {
                    p0s = fmaf(acc[m][n][j], asv[n], p0s);
                    p0d = fmaf(acc[m][n][j], adv[n], p0d);
                    p1s = fmaf(acc[m][n + 4][j], asv[n + 4], p1s);
                    p1d = fmaf(acc[m][n + 4][j], adv[n + 4], p1d);
                }
#pragma unroll
                for (int s = 8; s; s >>= 1) {
                    p0s += __shfl_xor(p0s, s, 16);
                    p0d += __shfl_xor(p0d, s, 16);
                    p1s += __shfl_xor(p1s, s, 16);
                    p1d += __shfl_xor(p1d, s, 16);
                }
                if (r15 == 0 && ok) {
                    ES[row * 4 + wc * 2 + 0] = p0s;
                    ES[row * 4 + wc * 2 + 1] = p1s;
                    ED[row * 4 + wc * 2 + 0] = p0d;
                    ED[row * 4 + wc * 2 + 1] = p1d;
                }
            } else {
                float ps = 0.f, pd = 0.f;
#pragma unroll
                for (int n = 0; n < 8; n++) {
                    ps = fmaf(acc[m][n][j], asv[n], ps);
                    pd = fmaf(acc[m][n][j], adv[n], pd);
                }
#pragma unroll
                for (int s = 8; s; s >>= 1) {
                    ps += __shfl_xor(ps, s, 16);
                    pd += __shfl_xor(pd, s, 16);
                }
                if (r15 == 0) { red[0][lrow][wc] = ps; red[1][lrow][wc] = pd; }
            }
        }
    }
    if (NH == 1) {
        __syncthreads();
        if (t < 128) {
            int row = n0 + t;
            if (row < N_NODES_C) {
                ES[row] = red[0][t][0] + red[0][t][1];
                ED[row] = red[1][t][0] + red[1][t][1];
            }
        }
    }
}

// ---------------------------------------------------------------------------
// Fused per-dst softmax aggregation (r7 config + LDS edge-logit prologue).
// Block = 8 nodes; their CSR slots are contiguous. Prologue: threads gather
// ES[src]/ED[dst] for all block edges into LDS (one parallel round-trip).
// Main: 2 nodes/wave (32 lanes each), lane owns 8 ch (16B gathers), 4-wide
// unroll. Slots beyond ECAP (never in practice) take a global fallback.
// ---------------------------------------------------------------------------
#define ECAP 160
template <int NH, bool RELU>
__global__ __launch_bounds__(256) void agg_kernel(
        const __hip_bfloat16* __restrict__ H, const int* __restrict__ rowoff,
        const int* __restrict__ csr_src, const int* __restrict__ csr_dst,
        const float* __restrict__ ES, const float* __restrict__ ED,
        const float* __restrict__ bias, __hip_bfloat16* __restrict__ Out) {
    __shared__ float Els[ECAP * NH];
    __shared__ int   Sls[ECAP];
    __shared__ int   roff[9];
    int t = threadIdx.x;
    int n0 = blockIdx.x * 8;                          // grid*8 == N exactly
    if (t < 9) roff[t] = rowoff[n0 + t];
    __syncthreads();
    int beg0 = roff[0];
    int ne = roff[8] - beg0;
    int nl = (ne < ECAP) ? ne : ECAP;
    for (int j = t; j < nl; j += 256) {
        int slot = beg0 + j;
        int srcj = csr_src[slot];
        int dj   = csr_dst[slot];
        Sls[j] = srcj;
        if (NH == 4) {
            float4 es = *(const float4*)&ES[srcj * 4];
            float4 ed = *(const float4*)&ED[dj * 4];
            float e;
            e = es.x + ed.x; Els[j * 4 + 0] = (e > 0.f) ? e : 0.2f * e;
            e = es.y + ed.y; Els[j * 4 + 1] = (e > 0.f) ? e : 0.2f * e;
            e = es.z + ed.z; Els[j * 4 + 2] = (e > 0.f) ? e : 0.2f * e;
            e = es.w + ed.w; Els[j * 4 + 3] = (e > 0.f) ? e : 0.2f * e;
        } else {
            float e = ES[srcj] + ED[dj];
            Els[j] = (e > 0.f) ? e : 0.2f * e;
        }
    }
    __syncthreads();

    int g = t >> 5;
    int node = n0 + g;
    int l = t & 31;
    int c0 = l * 8;
    int head = (NH == 4) ? (l >> 3) : 0;
    int jb = roff[g] - beg0, je = roff[g + 1] - beg0;
    int jeF = (je < ECAP) ? je : ECAP;

    float m = -1e30f;
    for (int j = jb; j < jeF; j++) m = fmaxf(m, Els[j * NH + head]);
    if (je > ECAP) {                                  // never in practice
        float edv = ED[node * NH + head];
        for (int j = ECAP; j < je; j++) {
            float e = ES[csr_src[beg0 + j] * NH + head] + edv;
            e = (e > 0.f) ? e : 0.2f * e;
            m = fmaxf(m, e);
        }
    }

    float s = 0.f;
    float a[8];
#pragma unroll
    for (int i = 0; i < 8; i++) a[i] = 0.f;
    const unsigned short* Hu = (const unsigned short*)H;

#define ACC8(v, p) \
    a[0] = fmaf(p, bflo(v.x), a[0]); a[1] = fmaf(p, bfhi(v.x), a[1]); \
    a[2] = fmaf(p, bflo(v.y), a[2]); a[3] = fmaf(p, bfhi(v.y), a[3]); \
    a[4] = fmaf(p, bflo(v.z), a[4]); a[5] = fmaf(p, bfhi(v.z), a[5]); \
    a[6] = fmaf(p, bflo(v.w), a[6]); a[7] = fmaf(p, bfhi(v.w), a[7]);

    int j = jb;
    for (; j + 4 <= jeF; j += 4) {
        int s0 = Sls[j], s1 = Sls[j + 1], s2 = Sls[j + 2], s3 = Sls[j + 3];
        float e0 = Els[(j + 0) * NH + head], e1 = Els[(j + 1) * NH + head];
        float e2 = Els[(j + 2) * NH + head], e3 = Els[(j + 3) * NH + head];
        uint4 v0 = *(const uint4*)(Hu + (size_t)s0 * KDIM + c0);
        uint4 v1 = *(const uint4*)(Hu + (size_t)s1 * KDIM + c0);
        uint4 v2 = *(const uint4*)(Hu + (size_t)s2 * KDIM + c0);
        uint4 v3 = *(const uint4*)(Hu + (size_t)s3 * KDIM + c0);
        float p0 = __expf(e0 - m), p1 = __expf(e1 - m);
        float p2 = __expf(e2 - m), p3 = __expf(e3 - m);
        s += p0 + p1 + p2 + p3;
        ACC8(v0, p0)
        ACC8(v1, p1)
        ACC8(v2, p2)
        ACC8(v3, p3)
    }
    for (; j < jeF; j++) {
        int s0 = Sls[j];
        float e0 = Els[j * NH + head];
        uint4 v0 = *(const uint4*)(Hu + (size_t)s0 * KDIM + c0);
        float p0 = __expf(e0 - m);
        s += p0;
        ACC8(v0, p0)
    }
    if (je > ECAP) {                                  // never in practice
        float edv = ED[node * NH + head];
        for (int jj = ECAP; jj < je; jj++) {
            int sj = csr_src[beg0 + jj];
            float e = ES[sj * NH + head] + edv;
            e = (e > 0.f) ? e : 0.2f * e;
            float p = __expf(e - m);
            s += p;
            uint4 v = *(const uint4*)(Hu + (size_t)sj * KDIM + c0);
            ACC8(v, p)
        }
    }
#undef ACC8

    float inv = 1.f / s;
    float4 b0 = *(const float4*)&bias[c0];
    float4 b1 = *(const float4*)&bias[c0 + 4];
    float o[8];
    o[0] = fmaf(a[0], inv, b0.x); o[1] = fmaf(a[1], inv, b0.y);
    o[2] = fmaf(a[2], inv, b0.z); o[3] = fmaf(a[3], inv, b0.w);
    o[4] = fmaf(a[4], inv, b1.x); o[5] = fmaf(a[5], inv, b1.y);
    o[6] = fmaf(a[6], inv, b1.z); o[7] = fmaf(a[7], inv, b1.w);
    __hip_bfloat16 rb[8];
#pragma unroll
    for (int i = 0; i < 8; i++) {
        float v = RELU ? fmaxf(o[i], 0.f) : o[i];
        rb[i] = __float2bfloat16(v);
    }
    *(uint4*)&Out[(size_t)node * KDIM + c0] = *(uint4*)rb;
}

// ---------------------------------------------------------------------------
// Global max pool over graphs. 4 rows in flight (wave = row offset), uint2
// loads (4 bf16 channels/thread), LDS cross-wave combine.
// ---------------------------------------------------------------------------
__global__ __launch_bounds__(256) void pool_k(
        const __hip_bfloat16* __restrict__ O, const int* __restrict__ batch,
        float* __restrict__ out) {
    __shared__ int range[2];
    __shared__ float red[3][256];
    int g = blockIdx.x, k = threadIdx.x;
    if (k < 2) {
        int v = g + k;
        int lo = 0, hi = N_NODES_C;
        while (lo < hi) { int mid = (lo + hi) >> 1; if (batch[mid] < v) lo = mid + 1; else hi = mid; }
        range[k] = lo;
    }
    __syncthreads();
    int cg = k & 63;
    int ro = k >> 6;
    float m0 = -INFINITY, m1 = -INFINITY, m2 = -INFINITY, m3 = -INFINITY;
    const unsigned short* Ou = (const unsigned short*)O;
    for (int i = range[0] + ro; i < range[1]; i += 4) {
        uint2 v = *(const uint2*)(Ou + (size_t)i * KDIM + cg * 4);
        m0 = fmaxf(m0, bflo(v.x)); m1 = fmaxf(m1, bfhi(v.x));
        m2 = fmaxf(m2, bflo(v.y)); m3 = fmaxf(m3, bfhi(v.y));
    }
    if (ro) {
        red[ro - 1][cg * 4 + 0] = m0; red[ro - 1][cg * 4 + 1] = m1;
        red[ro - 1][cg * 4 + 2] = m2; red[ro - 1][cg * 4 + 3] = m3;
    }
    __syncthreads();
    if (ro == 0) {
        m0 = fmaxf(fmaxf(m0, red[0][cg * 4 + 0]), fmaxf(red[1][cg * 4 + 0], red[2][cg * 4 + 0]));
        m1 = fmaxf(fmaxf(m1, red[0][cg * 4 + 1]), fmaxf(red[1][cg * 4 + 1], red[2][cg * 4 + 1]));
        m2 = fmaxf(fmaxf(m2, red[0][cg * 4 + 2]), fmaxf(red[1][cg * 4 + 2], red[2][cg * 4 + 2]));
        m3 = fmaxf(fmaxf(m3, red[0][cg * 4 + 3]), fmaxf(red[1][cg * 4 + 3], red[2][cg * 4 + 3]));
        float4 o = make_float4(m0, m1, m2, m3);
        *(float4*)&out[(size_t)g * KDIM + cg * 4] = o;
    }
}

// ---------------------------------------------------------------------------
extern "C" void kernel_launch(void* const* d_in, const int* in_sizes, int n_in,
                              void* d_out, int out_size, void* d_ws, size_t ws_size,
                              hipStream_t stream) {
    const float* x     = (const float*)d_in[0];
    const int*   ei    = (const int*)d_in[1];
    const int*   batch = (const int*)d_in[2];
    const float* W1  = (const float*)d_in[3];
    const float* as1 = (const float*)d_in[4];
    const float* ad1 = (const float*)d_in[5];
    const float* b1  = (const float*)d_in[6];
    const float* W2  = (const float*)d_in[7];
    const float* as2 = (const float*)d_in[8];
    const float* ad2 = (const float*)d_in[9];
    const float* b2  = (const float*)d_in[10];
    const float* W3  = (const float*)d_in[11];
    const float* as3 = (const float*)d_in[12];
    const float* ad3 = (const float*)d_in[13];
    const float* b3  = (const float*)d_in[14];
    float* out = (float*)d_out;

    // Workspace layout (~127 MB)
    char* p = (char*)d_ws;
    auto alloc = [&](size_t bytes) { char* r = p; p += (bytes + 255) & ~(size_t)255; return r; };
    __hip_bfloat16* Xb  = (__hip_bfloat16*)alloc((size_t)N_NODES_C * 64 * 2);
    __hip_bfloat16* Hb  = (__hip_bfloat16*)alloc((size_t)N_NODES_C * KDIM * 2);
    __hip_bfloat16* Nb  = (__hip_bfloat16*)alloc((size_t)N_NODES_C * KDIM * 2);
    __hip_bfloat16* Wt1 = (__hip_bfloat16*)alloc(256 * 64 * 2);
    __hip_bfloat16* Wt2 = (__hip_bfloat16*)alloc(256 * 256 * 2);
    __hip_bfloat16* Wt3 = (__hip_bfloat16*)alloc(256 * 256 * 2);
    float* ES     = (float*)alloc((size_t)N_NODES_C * 4 * 4);
    float* ED     = (float*)alloc((size_t)N_NODES_C * 4 * 4);
    int* degcur   = (int*)alloc((size_t)(2 * N_NODES_C + 1) * 4);   // deg + cursor, one memset
    int* deg      = degcur;
    int* cursor   = degcur + (N_NODES_C + 1);
    int* rowoff   = (int*)alloc((N_NODES_C + 1) * 4);
    int* csr      = (int*)alloc((size_t)E_TOT * 4 + 256);   // +pad
    int* csrd     = (int*)alloc((size_t)E_TOT * 4);
    int* partials = (int*)alloc(512 * 4);

    // --- zero deg+cursor, then conversions + degree count in one kernel ---
    hipMemsetAsync(degcur, 0, (size_t)(2 * N_NODES_C + 1) * 4, stream);
    int ctot = XE + W1E + 2 * WBE;
    conv_all_count<<<(ctot + 255) / 256, 256, 0, stream>>>(
        x, W1, W2, W3, ei, Xb, Wt1, Wt2, Wt3, deg);

    // --- CSR offsets (2-kernel scan) + scatter ---
    int nb = (N_NODES_C + 1 + 255) / 256;           // 391
    scan_chunk<<<nb, 256, 0, stream>>>(deg, rowoff, partials, N_NODES_C + 1);
    scan_fix<<<nb, 256, 0, stream>>>(rowoff, partials, N_NODES_C + 1);
    int egrid = (E_TOT + 255) / 256;
    scatter_k<<<egrid, 256, 0, stream>>>(ei, rowoff, cursor, csr, csrd);

    int ggrid = (N_NODES_C + 127) / 128;             // 782
    int agrid = N_NODES_C / 8;                       // 12500 (exact)
    // --- layer 1: 58(->64) -> 4x64, relu ---
    gemm_mfma<64, 4><<<ggrid, 256, 0, stream>>>(Xb, Wt1, as1, ad1, Hb, ES, ED);
    agg_kernel<4, true><<<agrid, 256, 0, stream>>>(Hb, rowoff, csr, csrd, ES, ED, b1, Nb);
    // --- layer 2: 256 -> 4x64, relu ---
    gemm_mfma<256, 4><<<ggrid, 256, 0, stream>>>(Nb, Wt2, as2, ad2, Hb, ES, ED);
    agg_kernel<4, true><<<agrid, 256, 0, stream>>>(Hb, rowoff, csr, csrd, ES, ED, b2, Nb);
    // --- layer 3: 256 -> 1x256, no relu ---
    gemm_mfma<256, 1><<<ggrid, 256, 0, stream>>>(Nb, Wt3, as3, ad3, Hb, ES, ED);
    agg_kernel<1, false><<<agrid, 256, 0, stream>>>(Hb, rowoff, csr, csrd, ES, ED, b3, Nb);
    // --- global max pool ---
    pool_k<<<N_GRAPHS_C, 256, 0, stream>>>(Nb, batch, out);
}